// Round 1
// 455.353 us; speedup vs baseline: 1.0265x; 1.0265x over previous
//
#include <hip/hip_runtime.h>
#include <hip/hip_bf16.h>
#include <stdint.h>

// E=16 experts, C=256, CAP=4 -> F=1024, B=8, L=1024
#define EE 16
#define CC 256
#define FF 1024
#define LL 1024
#define BB 8
#define TL 128            // L-tile per block
#define FC 32             // f-chunk
#define NCH 32            // FF/FC
#define HSTR 40           // h row stride (bf16): 80 B, 16B-aligned for b128

typedef __bf16 bf16x8 __attribute__((ext_vector_type(8)));
typedef __bf16 bf16x4 __attribute__((ext_vector_type(4)));
typedef float  f32x4  __attribute__((ext_vector_type(4)));

__device__ __forceinline__ f32x4 mfma16(bf16x8 a, bf16x8 b, f32x4 c) {
    return __builtin_amdgcn_mfma_f32_16x16x32_bf16(a, b, c, 0, 0, 0);
}

// async global->LDS, 16B per lane; lds dest = wave-uniform base + lane*16
__device__ __forceinline__ void gld_lds16(const __bf16* g, __bf16* l) {
    __builtin_amdgcn_global_load_lds(
        (const __attribute__((address_space(1))) void*)g,
        (__attribute__((address_space(3))) void*)l, 16, 0, 0);
}

// ---- merged weight pre-permute (fp32 -> bf16, granule-transposed) ----
// Coalesced read -> LDS transpose (padded) -> coalesced write.
// blocks 0..511:  W1 tile (e,ch) = bid      ws1[(((e*32+ch)*32+cg)*32+f)*8+j] = W1[(e*1024+ch*32+f)*256 + cg*8 + j]
// blocks 512..1023: W2 tile = bid-512       ws2[(((e*32+ch)*4+fg)*256+c)*8+j] = W2[(e*256+c)*1024 + ch*32 + fg*8 + j]
__global__ __launch_bounds__(256)
void cvt_both(const float* __restrict__ W1, const float* __restrict__ W2,
              __bf16* __restrict__ ws1, __bf16* __restrict__ ws2)
{
    __shared__ __align__(16) __bf16 ls[8448];
    const int t = threadIdx.x;
    const int bid = blockIdx.x;
    if (bid < 512) {
        const float* src = W1 + (size_t)bid * 8192;   // 32 f-rows x 256 c, contiguous
        #pragma unroll
        for (int i = 0; i < 8; ++i) {
            const int p = t + 256 * i;                // float4 index
            const float4 v = *(const float4*)(src + 4 * p);
            const int f = p >> 6, c4 = p & 63;
            const int cg = c4 >> 1, j0 = (c4 & 1) * 4;
            bf16x4 o;
            o[0] = (__bf16)v.x; o[1] = (__bf16)v.y; o[2] = (__bf16)v.z; o[3] = (__bf16)v.w;
            *(bf16x4*)(ls + cg * 264 + f * 8 + j0) = o;   // pad 264: kills 16-way conflict
        }
        __syncthreads();
        __bf16* dst = ws1 + (size_t)bid * 8192;
        #pragma unroll
        for (int i = 0; i < 4; ++i) {
            const int G = t + 256 * i;                // local granule = cg*32+f
            const int cg = G >> 5, f = G & 31;
            *(bf16x8*)(dst + (size_t)G * 8) = *(const bf16x8*)(ls + cg * 264 + f * 8);
        }
    } else {
        const int tile = bid - 512;
        const float* src = W2 + (size_t)(tile >> 5) * 262144 + (tile & 31) * 32;
        #pragma unroll
        for (int i = 0; i < 8; ++i) {
            const int u = t + 256 * i;
            const int c = u >> 3, col4 = u & 7;       // 8 float4 per 32-float row
            const float4 v = *(const float4*)(src + (size_t)c * 1024 + col4 * 4);
            const int fg = col4 >> 1, j0 = (col4 & 1) * 4;
            bf16x4 o;
            o[0] = (__bf16)v.x; o[1] = (__bf16)v.y; o[2] = (__bf16)v.z; o[3] = (__bf16)v.w;
            *(bf16x4*)(ls + fg * 2056 + c * 8 + j0) = o;  // pad 2056: spreads fg banks
        }
        __syncthreads();
        __bf16* dst = ws2 + (size_t)tile * 8192;
        #pragma unroll
        for (int i = 0; i < 4; ++i) {
            const int G = t + 256 * i;                // local granule = fg*256+c
            const int fg = G >> 8, c = G & 255;
            *(bf16x8*)(dst + (size_t)G * 8) = *(const bf16x8*)(ls + fg * 2056 + c * 8);
        }
    }
}

// Fused expert MLP. Block = (b, e, 128-l tile), 16 waves, producer/consumer split.
// Waves 0-7  (producers): GEMM1 for chunk ch   -> silu -> sH[ch&1].   Hold x frags (64 VGPR).
// Waves 8-15 (consumers): GEMM2 for chunk ch-1 from sH[(ch-1)&1].     Hold y accum (64 VGPR).
// Each wave owns 32 l-columns (2 MFMA n-tiles) => every LDS weight fragment feeds 2 MFMAs.
// LDS weight read volume per iter: 272 KB -> 144 KB (the prior bottleneck).
__global__ __launch_bounds__(1024, 4)
void experts_kernel(const float* __restrict__ x,
                    const __bf16* __restrict__ w1ws,
                    const float* __restrict__ b1,
                    const __bf16* __restrict__ w2ws,
                    const float* __restrict__ b2,
                    float* __restrict__ out)
{
    __shared__ __align__(16) __bf16 sW1[3][FC * CC];      // 48 KB, [cgran32][f32][8]
    __shared__ __align__(16) __bf16 sW2[3][CC * FC];      // 48 KB, [fgran4][c256][8]
    __shared__ __align__(16) __bf16 sH[2][4][32 * HSTR];  // 20 KB, [par][lw][row l][col f]

    const int tid  = threadIdx.x;
    const int lane = tid & 63;
    const int w    = tid >> 6;          // 0..15
    const int l15  = lane & 15, q4 = lane >> 4;
    const bool prod = (w < 8);
    const int fh   = w & 1;             // producer: f-half of chunk; consumer: c-half
    const int lw   = (w & 7) >> 1;      // 0..3: which 32-l range

    const int bid  = blockIdx.x;
    const int e    = ((bid & 7) << 1) | ((bid >> 3) & 1);  // 2 experts per XCD
    const int rest = bid >> 4;
    const int bb   = rest & 7;
    const int l0   = (rest >> 3) * TL;
    const int lb   = l0 + 32 * lw;

    const __bf16* w1c = w1ws + (size_t)e * (NCH * FC * CC);
    const __bf16* w2c = w2ws + (size_t)e * (NCH * CC * FC);
    const int slice = w * 512;          // 1 KB per wave

    // prologue: stage chunks 0,1  (chunk m -> buffer m%3)
    gld_lds16(w1c + 0 * 8192 + slice + lane * 8, &sW1[0][slice]);
    gld_lds16(w2c + 0 * 8192 + slice + lane * 8, &sW2[0][slice]);
    gld_lds16(w1c + 1 * 8192 + slice + lane * 8, &sW1[1][slice]);
    gld_lds16(w2c + 1 * 8192 + slice + lane * 8, &sW2[1][slice]);

    // Shared 64-VGPR pool: producers = x fragments (bf16x8 via bit_cast),
    // consumers = y accumulators (f32x4). Overlay keeps block VGPR <= 128.
    f32x4 st[2][8];
    if (prod) {
        // x frags: B-layout, n=l15 (+16*lt), k(c) = 32*ks + 8*q4 + u
        const float* xp = x + ((size_t)(bb * EE + e) * CC) * LL + lb + l15;
        #pragma unroll
        for (int lt = 0; lt < 2; ++lt) {
            #pragma unroll
            for (int ks = 0; ks < 8; ++ks) {
                bf16x8 f;
                #pragma unroll
                for (int u = 0; u < 8; ++u)
                    f[u] = (__bf16)xp[(size_t)(32 * ks + 8 * q4 + u) * LL + 16 * lt];
                st[lt][ks] = __builtin_bit_cast(f32x4, f);
            }
        }
    } else {
        #pragma unroll
        for (int lt = 0; lt < 2; ++lt)
            #pragma unroll
            for (int u = 0; u < 8; ++u) st[lt][u] = f32x4{0.f, 0.f, 0.f, 0.f};
    }

    __syncthreads();  // drains prologue DMA

    int rp = 0;  // producer read buf = ch%3
    #pragma unroll 1
    for (int ch = 0; ch <= NCH; ++ch) {
        // (ch+2)%3 == (ch-1)%3: stage target AND consumer read buf.
        // Safe: consumer reads are pre-barrier, stage issue is post-barrier.
        const int rq = (rp >= 1) ? rp - 1 : 2;

        if (prod) {
            if (ch < NCH) {
                // ---- GEMM1: h[f-half, my 32 l] over K=C=256, A reused x2 ----
                const float4 bv = *(const float4*)(b1 + e * FF + ch * FC + 16 * fh + 4 * q4);
                f32x4 a0 = f32x4{0.f, 0.f, 0.f, 0.f};
                f32x4 a1 = f32x4{0.f, 0.f, 0.f, 0.f};
                const __bf16* a1base = &sW1[rp][(16 * fh + l15) * 8];
                __builtin_amdgcn_s_setprio(1);
                #pragma unroll
                for (int ks = 0; ks < 8; ++ks) {
                    bf16x8 a = *(const bf16x8*)(a1base + (4 * ks + q4) * 256);
                    a0 = mfma16(a, __builtin_bit_cast(bf16x8, st[0][ks]), a0);
                    a1 = mfma16(a, __builtin_bit_cast(bf16x8, st[1][ks]), a1);
                }
                __builtin_amdgcn_s_setprio(0);
                // bias + SiLU -> sH rows [lt*16+l15], cols [16fh+4q4..+3]
                __bf16* hrow = &sH[ch & 1][lw][l15 * HSTR + 16 * fh + 4 * q4];
                bf16x4 hv;
                #pragma unroll
                for (int r = 0; r < 4; ++r) {
                    float v = a0[r] + ((const float*)&bv)[r];
                    hv[r] = (__bf16)(v / (1.0f + __expf(-v)));
                }
                *(bf16x4*)hrow = hv;
                #pragma unroll
                for (int r = 0; r < 4; ++r) {
                    float v = a1[r] + ((const float*)&bv)[r];
                    hv[r] = (__bf16)(v / (1.0f + __expf(-v)));
                }
                *(bf16x4*)(hrow + 16 * HSTR) = hv;
            }
        } else if (ch >= 1) {
            // ---- GEMM2: y[c-half, my 32 l] += W2[c, chunk ch-1] @ h(ch-1) ----
            const __bf16* hbase = &sH[(ch & 1) ^ 1][lw][l15 * HSTR + 8 * q4];
            bf16x8 h0 = *(const bf16x8*)(hbase);
            bf16x8 h1 = *(const bf16x8*)(hbase + 16 * HSTR);
            const __bf16* a2base = &sW2[rq][(128 * fh + l15) * 8];
            __builtin_amdgcn_s_setprio(1);
            #pragma unroll
            for (int u = 0; u < 8; ++u) {
                bf16x8 a = *(const bf16x8*)(a2base + (q4 * 256 + 16 * u) * 8);
                st[0][u] = mfma16(a, h0, st[0][u]);
                st[1][u] = mfma16(a, h1, st[1][u]);
            }
            __builtin_amdgcn_s_setprio(0);
        }

        if (ch < NCH) {
            __syncthreads();  // h(ch) visible; chunk ch+1 DMA drained
            // stage chunk ch+2 (distance 2; buffer rq just freed pre-barrier)
            if (ch + 2 < NCH) {
                gld_lds16(w1c + (size_t)(ch + 2) * 8192 + slice + lane * 8, &sW1[rq][slice]);
                gld_lds16(w2c + (size_t)(ch + 2) * 8192 + slice + lane * 8, &sW2[rq][slice]);
            }
        }
        rp = (rp >= 2) ? 0 : rp + 1;
    }

    // ---- epilogue (consumers only): + b2, fp32 stores (16-lane 64B segments) ----
    if (!prod) {
        float* outp = out + ((size_t)(bb * EE + e) * CC) * LL + lb + l15;
        #pragma unroll
        for (int u = 0; u < 8; ++u) {
            const int c0 = 128 * fh + 16 * u + 4 * q4;
            const float4 b2v = *(const float4*)(b2 + e * CC + c0);
            #pragma unroll
            for (int lt = 0; lt < 2; ++lt) {
                #pragma unroll
                for (int r = 0; r < 4; ++r)
                    __builtin_nontemporal_store(
                        st[lt][u][r] + ((const float*)&b2v)[r],
                        outp + (size_t)(c0 + r) * LL + 16 * lt);
            }
        }
    }
}

extern "C" void kernel_launch(void* const* d_in, const int* in_sizes, int n_in,
                              void* d_out, int out_size, void* d_ws, size_t ws_size,
                              hipStream_t stream)
{
    const float* x  = (const float*)d_in[0];
    const float* W1 = (const float*)d_in[1];
    const float* b1 = (const float*)d_in[2];
    const float* W2 = (const float*)d_in[3];
    const float* b2 = (const float*)d_in[4];
    float* out = (float*)d_out;

    const size_t nW1 = (size_t)EE * FF * CC;   // 4194304 elems
    __bf16* w1bf = (__bf16*)d_ws;              // 8.39 MB
    __bf16* w2bf = w1bf + nW1;                 // + 8.39 MB  (ws_size >= 16.8 MB, verified R1)

    cvt_both<<<dim3(1024), dim3(256), 0, stream>>>(W1, W2, w1bf, w2bf);

    experts_kernel<<<dim3(BB * EE * (LL / TL)), dim3(1024), 0, stream>>>(
        x, w1bf, b1, w2bf, b2, out);
}